// Round 8
// baseline (283.620 us; speedup 1.0000x reference)
//
#include <hip/hip_runtime.h>
#include <stdint.h>

// Problem constants
#define DIMC   768
#define NHEAD  12
#define HDIM   64
#define BATCH  8
#define SEQ    1024
#define NTOK   (BATCH*SEQ)      // 8192
#define QKVN   (3*DIMC)         // 2304
// Q is pre-scaled by 0.125 * log2(e) so softmax is exp2(S) directly.
#define QSCALE 0.18033688011112042f

typedef unsigned short u16;
typedef __attribute__((ext_vector_type(8))) __bf16 bf16x8;
typedef __attribute__((ext_vector_type(2))) __bf16 bf16x2;
typedef __attribute__((ext_vector_type(4))) float  f32x4;

#define MFMA16(a,b,c) __builtin_amdgcn_mfma_f32_16x16x32_bf16(a,b,c,0,0,0)

__device__ __forceinline__ u16 f2bf(float f) {
  union { float f; uint32_t u; } v; v.f = f;
  uint32_t u = v.u;
  u += 0x7fffu + ((u >> 16) & 1u);   // RN-even
  return (u16)(u >> 16);
}

__device__ __forceinline__ uint32_t pack2(float a, float b) {
  bf16x2 t = { (__bf16)a, (__bf16)b };
  uint32_t r; __builtin_memcpy(&r, &t, 4); return r;
}

// ---------------- fused fp32 -> bf16 convert ----------------
#define NX  (NTOK*DIMC)      // 6291456
#define NWQ (QKVN*DIMC)      // 1769472
#define NWP (DIMC*DIMC)      // 589824
__global__ __launch_bounds__(256)
void cvt_all(const float* __restrict__ x, const float* __restrict__ wq,
             const float* __restrict__ wp, u16* __restrict__ dst) {
  int i = (blockIdx.x * 256 + threadIdx.x) * 8;
  const float* src;
  int off;
  if (i < NX)            { src = x;  off = i; }
  else if (i < NX + NWQ) { src = wq; off = i - NX; }
  else                   { src = wp; off = i - NX - NWQ; }
  float a[8];
  __builtin_memcpy(a, src + off, 32);
  u16 o[8];
#pragma unroll
  for (int k = 0; k < 8; ++k) o[k] = f2bf(a[k]);
  __builtin_memcpy(dst + i, o, 16);
}

// ---------------- NT GEMM: C[M,N] = A[M,K] * B[N,K]^T + bias ----------------
// BARRIER-FREE K-loop: fragments loaded DIRECTLY global->VGPR (16B/lane,
// 64B contiguous per 4-lane group; A rows L1/L2-hot, B fully L2-resident).
// No LDS, no __syncthreads in the loop -> compiler emits fine-grained
// vmcnt(N) pipelining (the thing the global_load_lds+barrier structure
// forbids, per the m97 ~20% drain plateau). Grid x = M-tiles so XCD c
// (dispatch ~ id%8) owns M-tiles ===c (mod 8): A partitioned across XCD L2s,
// B replicated (tiny). MODE 0: fp32 out. MODE 1 (128x128): QKV scatter
// epilogue via LDS bounce (the only LDS/barrier use).
template<int MODE, int BM, int BN>
__global__ __launch_bounds__(256)
void gemm_nt(const u16* __restrict__ A, const u16* __restrict__ B,
             const float* __restrict__ bias, float* __restrict__ outF,
             u16* __restrict__ Qb, u16* __restrict__ Kb, u16* __restrict__ Vt,
             int M, int N, int K) {
  constexpr int NI = BM / 32;                    // i-tiles per wave
  constexpr int NJ = BN / 32;                    // j-tiles per wave
  constexpr int SME = (MODE == 1) ? BM * BN : 16;
  __shared__ __align__(16) u16 smem[SME];
  const int tid = threadIdx.x;
  const int wave = tid >> 6, lane = tid & 63;
  const int quad = lane >> 4, l15 = lane & 15;
  const int bm = blockIdx.x * BM, bn = blockIdx.y * BN;
  const int wr = (wave >> 1) * (BM / 2), wc = (wave & 1) * (BN / 2);

  // per-fragment global base pointers (lane l15 = row/col, quad = k-segment)
  const u16* Ap[NI];
  const u16* Bp[NJ];
#pragma unroll
  for (int t = 0; t < NI; ++t)
    Ap[t] = A + (size_t)(bm + wr + t * 16 + l15) * K + quad * 8;
#pragma unroll
  for (int t = 0; t < NJ; ++t)
    Bp[t] = B + (size_t)(bn + wc + t * 16 + l15) * K + quad * 8;

  f32x4 acc[NI][NJ] = {};
  const int nk = K >> 5;                         // BK=32
#pragma unroll 4
  for (int kt = 0; kt < nk; ++kt) {
    bf16x8 af[NI], bfr[NJ];
#pragma unroll
    for (int t = 0; t < NI; ++t) __builtin_memcpy(&af[t], Ap[t] + kt * 32, 16);
#pragma unroll
    for (int t = 0; t < NJ; ++t) __builtin_memcpy(&bfr[t], Bp[t] + kt * 32, 16);
#pragma unroll
    for (int i = 0; i < NI; ++i)
#pragma unroll
      for (int j = 0; j < NJ; ++j)
        acc[i][j] = MFMA16(af[i], bfr[j], acc[i][j]);
  }

  // D[row=(lane>>4)*4+r][col=lane&15] per 16x16 tile (m89-verified)
  if (MODE == 0) {
#pragma unroll
    for (int i = 0; i < NI; ++i) {
      const int row0 = bm + wr + i * 16 + quad * 4;
#pragma unroll
      for (int j = 0; j < NJ; ++j) {
        const int col = bn + wc + j * 16 + l15;
        const float bv = bias[col];
#pragma unroll
        for (int r = 0; r < 4; ++r)
          outF[(size_t)(row0 + r) * N + col] = acc[i][j][r] + bv;
      }
    }
  } else {
    // ---- QKV epilogue (128x128): s block-uniform, LDS bounce, coalesced stores
    const int s = bn / DIMC;                 // 0=Q 1=K 2=V
    const int bnr = bn - s * DIMC;           // head-region offset (mult of 128)
    const int bb = bm >> 10;                 // batch
    const int nlo = bm & 1023;               // token base within batch
    u16* sC = smem;                          // 128x128 bf16 = 32KB
    float bv[NJ];
#pragma unroll
    for (int j = 0; j < NJ; ++j) bv[j] = bias[bn + wc + j * 16 + l15];

    if (s < 2) {
      const float sc = (s == 0) ? QSCALE : 1.0f;
      // sC[row][col], 16B-chunk swizzle: chunk' = (col>>3) ^ (row&15)
#pragma unroll
      for (int i = 0; i < NI; ++i) {
        const int rl = wr + i * 16 + quad * 4;
#pragma unroll
        for (int j = 0; j < NJ; ++j) {
          const int cl = wc + j * 16 + l15;
#pragma unroll
          for (int r = 0; r < 4; ++r) {
            const int row = rl + r;
            const int c2 = (cl >> 3) ^ (row & 15);
            sC[row * 128 + (c2 << 3) + (cl & 7)] = f2bf((acc[i][j][r] + bv[j]) * sc);
          }
        }
      }
      __syncthreads();
      u16* basep = (s == 0) ? Qb : Kb;
#pragma unroll
      for (int it = 0; it < 8; ++it) {
        const int idx = it * 256 + tid;
        const int row = idx >> 4, seg = idx & 15;
        const int c2 = seg ^ (row & 15);
        uint4 v = *(const uint4*)&sC[row * 128 + (c2 << 3)];
        const int colb = seg * 8;
        const int hh = (bnr + colb) >> 6, d = (bnr + colb) & 63;
        *(uint4*)(basep + (((size_t)(bb * NHEAD + hh) << 10) + nlo + row) * 64 + d) = v;
      }
    } else {
      // V transposed: sC[col][n], 16B-chunk (8 n) swizzle by col&15; 8B reg writes
#pragma unroll
      for (int i = 0; i < NI; ++i) {
        const int n0 = wr + i * 16 + quad * 4;
        const int c16 = n0 >> 3, off8 = (n0 >> 2) & 1;
#pragma unroll
        for (int j = 0; j < NJ; ++j) {
          const int cl = wc + j * 16 + l15;
          uint2 w = { pack2(acc[i][j][0] + bv[j], acc[i][j][1] + bv[j]),
                      pack2(acc[i][j][2] + bv[j], acc[i][j][3] + bv[j]) };
          *(uint2*)&sC[cl * 128 + ((c16 ^ (cl & 15)) << 3) + off8 * 4] = w;
        }
      }
      __syncthreads();
#pragma unroll
      for (int it = 0; it < 8; ++it) {
        const int idx = it * 256 + tid;
        const int colL = idx >> 4, seg = idx & 15;
        uint4 v = *(const uint4*)&sC[colL * 128 + ((seg ^ (colL & 15)) << 3)];
        const int hh = (bnr + colL) >> 6, d = (bnr + colL) & 63;
        *(uint4*)(Vt + (((size_t)((bb * NHEAD + hh) * 64 + d)) << 10) + nlo + seg * 8) = v;
      }
    }
  }
}

// ---------------- flash attention (no-max streaming softmax, S^T orientation) ----
// grid = B*H*8 = 768 blocks; block = 128 Q rows, 4 waves x 32 rows; 64-key chunks.
__device__ __forceinline__ int sw(int row, int chunk) {
  return row * 64 + ((chunk ^ (row & 7)) << 3);   // u16 offset
}

__global__ __launch_bounds__(256, 3)
void attn_fwd(const u16* __restrict__ Qb, const u16* __restrict__ Kb,
              const u16* __restrict__ Vt, u16* __restrict__ AO) {
  __shared__ __align__(16) u16 sK[64 * 64];        // [key][d], swizzled
  __shared__ __align__(16) u16 sV[64 * 64];        // [d][key], swizzled
  __shared__ __align__(16) u16 sP[4][32 * 64];     // per-wave [q][key], swizzled
  const int tid = threadIdx.x;
  const int wave = tid >> 6, lane = tid & 63;
  const int quad = lane >> 4, l15 = lane & 15;
  const int bid = blockIdx.x;
  const int qb = bid & 7, bh = bid >> 3;           // bh in [0,96)
  const int b = bh / NHEAD, h = bh - b * NHEAD;
  const u16* Qp = Qb + ((size_t)bh << 16);
  const u16* Kp = Kb + ((size_t)bh << 16);
  const u16* Vp = Vt + ((size_t)bh << 16);
  u16* sPw = sP[wave];
  const int qrow0 = qb * 128 + wave * 32;

  bf16x8 qf[2][2];
#pragma unroll
  for (int qt = 0; qt < 2; ++qt)
#pragma unroll
    for (int ks = 0; ks < 2; ++ks)
      __builtin_memcpy(&qf[qt][ks],
                       Qp + (qrow0 + qt * 16 + l15) * 64 + ks * 32 + quad * 8, 16);

  f32x4 oacc[4][2] = {};
  float Lsum[2] = {0.f, 0.f};

  for (int kc = 0; kc < 16; ++kc) {
    __syncthreads();
#pragma unroll
    for (int i = 0; i < 2; ++i) {
      const int g = i * 256 + tid, row = g >> 3, seg = g & 7;
      uint4 vk = *(const uint4*)(Kp + (kc << 12) + g * 8);
      uint4 vv = *(const uint4*)(Vp + (row << 10) + (kc << 6) + seg * 8);
      *(uint4*)&sK[sw(row, seg)] = vk;
      *(uint4*)&sV[sw(row, seg)] = vv;
    }
    __syncthreads();

    f32x4 st[4][2] = {};
#pragma unroll
    for (int ks = 0; ks < 2; ++ks) {
      bf16x8 kf[4];
#pragma unroll
      for (int kt = 0; kt < 4; ++kt)
        kf[kt] = *(const bf16x8*)&sK[sw(kt * 16 + l15, ks * 4 + quad)];
#pragma unroll
      for (int kt = 0; kt < 4; ++kt)
#pragma unroll
        for (int qt = 0; qt < 2; ++qt)
          st[kt][qt] = MFMA16(kf[kt], qf[qt][ks], st[kt][qt]);
    }

#pragma unroll
    for (int kt = 0; kt < 4; ++kt)
#pragma unroll
      for (int qt = 0; qt < 2; ++qt) {
        float p0 = __builtin_amdgcn_exp2f(st[kt][qt][0]);
        float p1 = __builtin_amdgcn_exp2f(st[kt][qt][1]);
        float p2 = __builtin_amdgcn_exp2f(st[kt][qt][2]);
        float p3 = __builtin_amdgcn_exp2f(st[kt][qt][3]);
        Lsum[qt] += (p0 + p1) + (p2 + p3);
        uint2 w = { pack2(p0, p1), pack2(p2, p3) };
        *(uint2*)&sPw[sw(qt * 16 + l15, kt * 2 + (quad >> 1)) + (quad & 1) * 4] = w;
      }

    __builtin_amdgcn_s_waitcnt(0);

#pragma unroll
    for (int ks = 0; ks < 2; ++ks) {
      bf16x8 vf[4], pf[2];
#pragma unroll
      for (int dt = 0; dt < 4; ++dt)
        vf[dt] = *(const bf16x8*)&sV[sw(dt * 16 + l15, ks * 4 + quad)];
#pragma unroll
      for (int qt = 0; qt < 2; ++qt)
        pf[qt] = *(const bf16x8*)&sPw[sw(qt * 16 + l15, ks * 4 + quad)];
#pragma unroll
      for (int dt = 0; dt < 4; ++dt)
#pragma unroll
        for (int qt = 0; qt < 2; ++qt)
          oacc[dt][qt] = MFMA16(vf[dt], pf[qt], oacc[dt][qt]);
    }
  }

  float inv[2];
#pragma unroll
  for (int qt = 0; qt < 2; ++qt) {
    float l = Lsum[qt];
    l += __shfl_xor(l, 16);
    l += __shfl_xor(l, 32);
    inv[qt] = 1.0f / l;
  }
#pragma unroll
  for (int dt = 0; dt < 4; ++dt)
#pragma unroll
    for (int qt = 0; qt < 2; ++qt) {
      const int n = qrow0 + qt * 16 + l15;
      uint2 w = { pack2(oacc[dt][qt][0] * inv[qt], oacc[dt][qt][1] * inv[qt]),
                  pack2(oacc[dt][qt][2] * inv[qt], oacc[dt][qt][3] * inv[qt]) };
      *(uint2*)(AO + (size_t)((b << 10) + n) * DIMC + h * 64 + dt * 16 + quad * 4) = w;
    }
}

// ---------------- launch ----------------
extern "C" void kernel_launch(void* const* d_in, const int* in_sizes, int n_in,
                              void* d_out, int out_size, void* d_ws, size_t ws_size,
                              hipStream_t stream) {
  const float* x      = (const float*)d_in[0];
  const float* w_qkv  = (const float*)d_in[1];
  const float* b_qkv  = (const float*)d_in[2];
  const float* w_proj = (const float*)d_in[3];
  const float* b_proj = (const float*)d_in[4];
  float* out = (float*)d_out;

  u16* Xb     = (u16*)d_ws;
  u16* Wqkvb  = Xb + NX;
  u16* Wprojb = Wqkvb + NWQ;
  u16* Qb     = Wprojb + NWP;
  u16* Kb     = Qb + NX;
  u16* Vt     = Kb + NX;
  u16* AO     = Vt + NX;

  cvt_all<<<(NX + NWQ + NWP) / 2048, 256, 0, stream>>>(x, w_qkv, w_proj, Xb);

  // grid.x = M-tiles (fastest) -> XCD-partitioned A, replicated B
  dim3 g1(NTOK / 128, QKVN / 128);   // (64, 18)
  gemm_nt<1, 128, 128><<<g1, 256, 0, stream>>>(Xb, Wqkvb, b_qkv, nullptr, Qb, Kb, Vt,
                                               NTOK, QKVN, DIMC);

  attn_fwd<<<BATCH * NHEAD * (SEQ / 128), 256, 0, stream>>>(Qb, Kb, Vt, AO);

  dim3 g2(NTOK / 64, DIMC / 128);    // (128, 6) = 768 blocks = 3/CU
  gemm_nt<0, 64, 128><<<g2, 256, 0, stream>>>(AO, Wprojb, b_proj, out,
                                              nullptr, nullptr, nullptr,
                                              NTOK, DIMC, DIMC);
}

// Round 9
// 181.786 us; speedup vs baseline: 1.5602x; 1.5602x over previous
//
#include <hip/hip_runtime.h>
#include <stdint.h>

// Problem constants
#define DIMC   768
#define NHEAD  12
#define HDIM   64
#define BATCH  8
#define SEQ    1024
#define NTOK   (BATCH*SEQ)      // 8192
#define QKVN   (3*DIMC)         // 2304
// Q is pre-scaled by 0.125 * log2(e) so softmax is exp2(S) directly.
#define QSCALE 0.18033688011112042f

typedef unsigned short u16;
typedef __attribute__((ext_vector_type(8))) __bf16 bf16x8;
typedef __attribute__((ext_vector_type(2))) __bf16 bf16x2;
typedef __attribute__((ext_vector_type(4))) float  f32x4;

#define MFMA16(a,b,c) __builtin_amdgcn_mfma_f32_16x16x32_bf16(a,b,c,0,0,0)

__device__ __forceinline__ u16 f2bf(float f) {
  union { float f; uint32_t u; } v; v.f = f;
  uint32_t u = v.u;
  u += 0x7fffu + ((u >> 16) & 1u);   // RN-even
  return (u16)(u >> 16);
}

__device__ __forceinline__ uint32_t pack2(float a, float b) {
  bf16x2 t = { (__bf16)a, (__bf16)b };
  uint32_t r; __builtin_memcpy(&r, &t, 4); return r;
}

__device__ __forceinline__ void gload16(const void* g, void* l) {
  __builtin_amdgcn_global_load_lds((const __attribute__((address_space(1))) void*)g,
                                   (__attribute__((address_space(3))) void*)l,
                                   16, 0, 0);
}

// ---------------- fused fp32 -> bf16 convert ----------------
#define NX  (NTOK*DIMC)      // 6291456
#define NWQ (QKVN*DIMC)      // 1769472
#define NWP (DIMC*DIMC)      // 589824
__global__ __launch_bounds__(256)
void cvt_all(const float* __restrict__ x, const float* __restrict__ wq,
             const float* __restrict__ wp, u16* __restrict__ dst) {
  int i = (blockIdx.x * 256 + threadIdx.x) * 8;
  const float* src;
  int off;
  if (i < NX)            { src = x;  off = i; }
  else if (i < NX + NWQ) { src = wq; off = i - NX; }
  else                   { src = wp; off = i - NX - NWQ; }
  float a[8];
  __builtin_memcpy(a, src + off, 32);
  u16 o[8];
#pragma unroll
  for (int k = 0; k < 8; ++k) o[k] = f2bf(a[k]);
  __builtin_memcpy(dst + i, o, 16);
}

// ---------------- NT GEMM: C[M,N] = A[M,K] * B[N,K]^T + bias ----------------
// R7 structure: BK=32, double-buffered single-barrier K-loop, phase-aware
// swizzle chunk ^= (row>>1)&3 on the GLOBAL source (conflict-free b128 reads).
// NEW: 1-D grid, XCD-pinned decode — xcd c (dispatch ~ bid%8) owns M-tiles
// [8c,8c+8) x all N-tiles, so each XCD's A-stripe + B stay L2-resident.
// MODE 0: fp32 out.  MODE 1 (128x128 only): QKV epilogue via LDS bounce.
template<int MODE, int BM, int BN>
__global__ __launch_bounds__(256)
void gemm_nt(const u16* __restrict__ A, const u16* __restrict__ B,
             const float* __restrict__ bias, float* __restrict__ outF,
             u16* __restrict__ Qb, u16* __restrict__ Kb, u16* __restrict__ Vt,
             int M, int N, int K) {
  constexpr int NI = BM / 32;                    // i-tiles per wave
  constexpr int NJ = BN / 32;                    // j-tiles per wave
  constexpr int CHA = BM * 4;                    // 16B chunks per A stage
  constexpr int CHB = BN * 4;
  constexpr int LA = (CHA + 255) / 256;          // staging iters per thread
  constexpr int LB = (CHB + 255) / 256;
  constexpr int SME1 = 2 * (BM + BN) * 32;
  constexpr int SME = (MODE == 1 && BM * BN > SME1) ? BM * BN : SME1;
  __shared__ __align__(16) u16 smem[SME];
  u16* sA = smem;                                // 2 stages of BM x 32
  u16* sB = smem + 2 * BM * 32;                  // 2 stages of BN x 32
  const int tid = threadIdx.x;
  const int wave = tid >> 6, lane = tid & 63;
  const int quad = lane >> 4, l15 = lane & 15;
  // XCD-pinned decode: c = bid&7 -> M-tiles [8c, 8c+8), nt = g>>3
  const int bid = blockIdx.x;
  const int c = bid & 7, g = bid >> 3;
  const int bm = (c * 8 + (g & 7)) * BM;
  const int bn = (g >> 3) * BN;
  const int wr = (wave >> 1) * (BM / 2), wc = (wave & 1) * (BN / 2);

  // staging source addresses (seg swizzled by (row>>1)&3)
  const u16* Ag[LA];
  const u16* Bg[LB];
#pragma unroll
  for (int i = 0; i < LA; ++i) {
    const int gg = i * 256 + tid, row = gg >> 2, seg = (gg & 3) ^ ((row >> 1) & 3);
    Ag[i] = A + (size_t)(bm + (row < BM ? row : 0)) * K + seg * 8;
  }
#pragma unroll
  for (int i = 0; i < LB; ++i) {
    const int gg = i * 256 + tid, row = gg >> 2, seg = (gg & 3) ^ ((row >> 1) & 3);
    Bg[i] = B + (size_t)(bn + (row < BN ? row : 0)) * K + seg * 8;
  }

  const int nk = K >> 5;                         // BK=32

  // prologue: stage kt=0 into stage 0
#pragma unroll
  for (int i = 0; i < LA; ++i) {
    const int gg = i * 256 + tid;
    if (CHA % 256 == 0 || gg < CHA) gload16(Ag[i], sA + gg * 8);
  }
#pragma unroll
  for (int i = 0; i < LB; ++i) {
    const int gg = i * 256 + tid;
    if (CHB % 256 == 0 || gg < CHB) gload16(Bg[i], sB + gg * 8);
  }

  f32x4 acc[NI][NJ] = {};
  for (int kt = 0; kt < nk; ++kt) {
    __syncthreads();                 // vmcnt(0) drain: stage(kt) complete
    if (kt + 1 < nk) {               // prefetch stage kt+1, overlapped w/ compute
      const int st = (kt + 1) & 1;
#pragma unroll
      for (int i = 0; i < LA; ++i) {
        const int gg = i * 256 + tid;
        if (CHA % 256 == 0 || gg < CHA)
          gload16(Ag[i] + (kt + 1) * 32, sA + st * BM * 32 + gg * 8);
      }
#pragma unroll
      for (int i = 0; i < LB; ++i) {
        const int gg = i * 256 + tid;
        if (CHB % 256 == 0 || gg < CHB)
          gload16(Bg[i] + (kt + 1) * 32, sB + st * BN * 32 + gg * 8);
      }
    }
    const int st0 = kt & 1;
    bf16x8 af[NI], bfr[NJ];
#pragma unroll
    for (int t = 0; t < NI; ++t) {
      const int r = wr + t * 16 + l15;
      __builtin_memcpy(&af[t],
        &sA[st0 * BM * 32 + r * 32 + ((quad ^ ((r >> 1) & 3)) << 3)], 16);
    }
#pragma unroll
    for (int t = 0; t < NJ; ++t) {
      const int r = wc + t * 16 + l15;
      __builtin_memcpy(&bfr[t],
        &sB[st0 * BN * 32 + r * 32 + ((quad ^ ((r >> 1) & 3)) << 3)], 16);
    }
#pragma unroll
    for (int i = 0; i < NI; ++i)
#pragma unroll
      for (int j = 0; j < NJ; ++j)
        acc[i][j] = MFMA16(af[i], bfr[j], acc[i][j]);
  }

  // D[row=(lane>>4)*4+r][col=lane&15] per 16x16 tile (m89-verified)
  if (MODE == 0) {
#pragma unroll
    for (int i = 0; i < NI; ++i) {
      const int row0 = bm + wr + i * 16 + quad * 4;
#pragma unroll
      for (int j = 0; j < NJ; ++j) {
        const int col = bn + wc + j * 16 + l15;
        const float bv = bias[col];
#pragma unroll
        for (int r = 0; r < 4; ++r)
          outF[(size_t)(row0 + r) * N + col] = acc[i][j][r] + bv;
      }
    }
  } else {
    // ---- QKV epilogue (128x128): s block-uniform, LDS bounce, coalesced stores
    const int s = bn / DIMC;                 // 0=Q 1=K 2=V
    const int bnr = bn - s * DIMC;           // head-region offset (mult of 128)
    const int bb = bm >> 10;                 // batch
    const int nlo = bm & 1023;               // token base within batch
    u16* sC = smem;                          // 128x128 bf16 = 32KB
    float bv[NJ];
#pragma unroll
    for (int j = 0; j < NJ; ++j) bv[j] = bias[bn + wc + j * 16 + l15];
    __syncthreads();                         // all K-loop LDS reads done

    if (s < 2) {
      const float sc = (s == 0) ? QSCALE : 1.0f;
      // sC[row][col], 16B-chunk swizzle: chunk' = (col>>3) ^ (row&15)
#pragma unroll
      for (int i = 0; i < NI; ++i) {
        const int rl = wr + i * 16 + quad * 4;
#pragma unroll
        for (int j = 0; j < NJ; ++j) {
          const int cl = wc + j * 16 + l15;
#pragma unroll
          for (int r = 0; r < 4; ++r) {
            const int row = rl + r;
            const int c2 = (cl >> 3) ^ (row & 15);
            sC[row * 128 + (c2 << 3) + (cl & 7)] = f2bf((acc[i][j][r] + bv[j]) * sc);
          }
        }
      }
      __syncthreads();
      u16* basep = (s == 0) ? Qb : Kb;
#pragma unroll
      for (int it = 0; it < 8; ++it) {
        const int idx = it * 256 + tid;
        const int row = idx >> 4, seg = idx & 15;
        const int c2 = seg ^ (row & 15);
        uint4 v = *(const uint4*)&sC[row * 128 + (c2 << 3)];
        const int colb = seg * 8;
        const int hh = (bnr + colb) >> 6, d = (bnr + colb) & 63;
        *(uint4*)(basep + (((size_t)(bb * NHEAD + hh) << 10) + nlo + row) * 64 + d) = v;
      }
    } else {
      // V transposed: sC[col][n], 16B-chunk (8 n) swizzle by col&15; 8B reg writes
#pragma unroll
      for (int i = 0; i < NI; ++i) {
        const int n0 = wr + i * 16 + quad * 4;
        const int c16 = n0 >> 3, off8 = (n0 >> 2) & 1;
#pragma unroll
        for (int j = 0; j < NJ; ++j) {
          const int cl = wc + j * 16 + l15;
          uint2 w = { pack2(acc[i][j][0] + bv[j], acc[i][j][1] + bv[j]),
                      pack2(acc[i][j][2] + bv[j], acc[i][j][3] + bv[j]) };
          *(uint2*)&sC[cl * 128 + ((c16 ^ (cl & 15)) << 3) + off8 * 4] = w;
        }
      }
      __syncthreads();
#pragma unroll
      for (int it = 0; it < 8; ++it) {
        const int idx = it * 256 + tid;
        const int colL = idx >> 4, seg = idx & 15;
        uint4 v = *(const uint4*)&sC[colL * 128 + ((seg ^ (colL & 15)) << 3)];
        const int hh = (bnr + colL) >> 6, d = (bnr + colL) & 63;
        *(uint4*)(Vt + (((size_t)((bb * NHEAD + hh) * 64 + d)) << 10) + nlo + seg * 8) = v;
      }
    }
  }
}

// ---------------- flash attention (no-max streaming softmax, S^T orientation) ----
// 768 blocks; XCD-pinned: xcd c owns bh in [12c, 12c+12) (all 8 q-blocks of a
// bh on one XCD -> K/V 3MB per XCD stays L2-resident, fetched once).
__device__ __forceinline__ int sw(int row, int chunk) {
  return row * 64 + ((chunk ^ (row & 7)) << 3);   // u16 offset
}

__global__ __launch_bounds__(256, 3)
void attn_fwd(const u16* __restrict__ Qb, const u16* __restrict__ Kb,
              const u16* __restrict__ Vt, u16* __restrict__ AO) {
  __shared__ __align__(16) u16 sK[64 * 64];        // [key][d], swizzled
  __shared__ __align__(16) u16 sV[64 * 64];        // [d][key], swizzled
  __shared__ __align__(16) u16 sP[4][32 * 64];     // per-wave [q][key], swizzled
  const int tid = threadIdx.x;
  const int wave = tid >> 6, lane = tid & 63;
  const int quad = lane >> 4, l15 = lane & 15;
  const int bid = blockIdx.x;
  const int c = bid & 7, g = bid >> 3;             // g in [0,96)
  const int bh = c * 12 + g % 12;                  // bh in [0,96)
  const int qb = g / 12;                           // q-block in [0,8)
  const int b = bh / NHEAD, h = bh - b * NHEAD;
  const u16* Qp = Qb + ((size_t)bh << 16);
  const u16* Kp = Kb + ((size_t)bh << 16);
  const u16* Vp = Vt + ((size_t)bh << 16);
  u16* sPw = sP[wave];
  const int qrow0 = qb * 128 + wave * 32;

  bf16x8 qf[2][2];
#pragma unroll
  for (int qt = 0; qt < 2; ++qt)
#pragma unroll
    for (int ks = 0; ks < 2; ++ks)
      __builtin_memcpy(&qf[qt][ks],
                       Qp + (qrow0 + qt * 16 + l15) * 64 + ks * 32 + quad * 8, 16);

  f32x4 oacc[4][2] = {};
  float Lsum[2] = {0.f, 0.f};

  for (int kc = 0; kc < 16; ++kc) {
    __syncthreads();
#pragma unroll
    for (int i = 0; i < 2; ++i) {
      const int gg = i * 256 + tid, row = gg >> 3, seg = gg & 7;
      uint4 vk = *(const uint4*)(Kp + (kc << 12) + gg * 8);
      uint4 vv = *(const uint4*)(Vp + (row << 10) + (kc << 6) + seg * 8);
      *(uint4*)&sK[sw(row, seg)] = vk;
      *(uint4*)&sV[sw(row, seg)] = vv;
    }
    __syncthreads();

    f32x4 st[4][2] = {};
#pragma unroll
    for (int ks = 0; ks < 2; ++ks) {
      bf16x8 kf[4];
#pragma unroll
      for (int kt = 0; kt < 4; ++kt)
        kf[kt] = *(const bf16x8*)&sK[sw(kt * 16 + l15, ks * 4 + quad)];
#pragma unroll
      for (int kt = 0; kt < 4; ++kt)
#pragma unroll
        for (int qt = 0; qt < 2; ++qt)
          st[kt][qt] = MFMA16(kf[kt], qf[qt][ks], st[kt][qt]);
    }

#pragma unroll
    for (int kt = 0; kt < 4; ++kt)
#pragma unroll
      for (int qt = 0; qt < 2; ++qt) {
        float p0 = __builtin_amdgcn_exp2f(st[kt][qt][0]);
        float p1 = __builtin_amdgcn_exp2f(st[kt][qt][1]);
        float p2 = __builtin_amdgcn_exp2f(st[kt][qt][2]);
        float p3 = __builtin_amdgcn_exp2f(st[kt][qt][3]);
        Lsum[qt] += (p0 + p1) + (p2 + p3);
        uint2 w = { pack2(p0, p1), pack2(p2, p3) };
        *(uint2*)&sPw[sw(qt * 16 + l15, kt * 2 + (quad >> 1)) + (quad & 1) * 4] = w;
      }

    __builtin_amdgcn_s_waitcnt(0);

#pragma unroll
    for (int ks = 0; ks < 2; ++ks) {
      bf16x8 vf[4], pf[2];
#pragma unroll
      for (int dt = 0; dt < 4; ++dt)
        vf[dt] = *(const bf16x8*)&sV[sw(dt * 16 + l15, ks * 4 + quad)];
#pragma unroll
      for (int qt = 0; qt < 2; ++qt)
        pf[qt] = *(const bf16x8*)&sPw[sw(qt * 16 + l15, ks * 4 + quad)];
#pragma unroll
      for (int dt = 0; dt < 4; ++dt)
#pragma unroll
        for (int qt = 0; qt < 2; ++qt)
          oacc[dt][qt] = MFMA16(vf[dt], pf[qt], oacc[dt][qt]);
    }
  }

  float inv[2];
#pragma unroll
  for (int qt = 0; qt < 2; ++qt) {
    float l = Lsum[qt];
    l += __shfl_xor(l, 16);
    l += __shfl_xor(l, 32);
    inv[qt] = 1.0f / l;
  }
#pragma unroll
  for (int dt = 0; dt < 4; ++dt)
#pragma unroll
    for (int qt = 0; qt < 2; ++qt) {
      const int n = qrow0 + qt * 16 + l15;
      uint2 w = { pack2(oacc[dt][qt][0] * inv[qt], oacc[dt][qt][1] * inv[qt]),
                  pack2(oacc[dt][qt][2] * inv[qt], oacc[dt][qt][3] * inv[qt]) };
      *(uint2*)(AO + (size_t)((b << 10) + n) * DIMC + h * 64 + dt * 16 + quad * 4) = w;
    }
}

// ---------------- launch ----------------
extern "C" void kernel_launch(void* const* d_in, const int* in_sizes, int n_in,
                              void* d_out, int out_size, void* d_ws, size_t ws_size,
                              hipStream_t stream) {
  const float* x      = (const float*)d_in[0];
  const float* w_qkv  = (const float*)d_in[1];
  const float* b_qkv  = (const float*)d_in[2];
  const float* w_proj = (const float*)d_in[3];
  const float* b_proj = (const float*)d_in[4];
  float* out = (float*)d_out;

  u16* Xb     = (u16*)d_ws;
  u16* Wqkvb  = Xb + NX;
  u16* Wprojb = Wqkvb + NWQ;
  u16* Qb     = Wprojb + NWP;
  u16* Kb     = Qb + NX;
  u16* Vt     = Kb + NX;
  u16* AO     = Vt + NX;

  cvt_all<<<(NX + NWQ + NWP) / 2048, 256, 0, stream>>>(x, w_qkv, w_proj, Xb);

  // 1-D XCD-pinned grids: 64 M-tiles x 18 N-tiles = 1152 blocks
  gemm_nt<1, 128, 128><<<1152, 256, 0, stream>>>(Xb, Wqkvb, b_qkv, nullptr,
                                                 Qb, Kb, Vt, NTOK, QKVN, DIMC);

  attn_fwd<<<768, 256, 0, stream>>>(Qb, Kb, Vt, AO);

  // 64 M-tiles x 8 N-tiles(96) = 512 blocks
  gemm_nt<0, 128, 96><<<512, 256, 0, stream>>>(AO, Wprojb, b_proj, out,
                                               nullptr, nullptr, nullptr,
                                               NTOK, DIMC, DIMC);
}